// Round 13
// baseline (289.259 us; speedup 1.0000x reference)
//
#include <hip/hip_runtime.h>
#include <math.h>

#define BB 2
#define NN 2048
#define DD 1024
#define HH 16
#define DK 64
#define LOG2E 1.4426950408889634f

typedef __attribute__((ext_vector_type(8))) short short8;
typedef __attribute__((ext_vector_type(4))) float f32x4;
typedef __attribute__((ext_vector_type(16))) float f32x16;
typedef __attribute__((ext_vector_type(4))) float f32x4v;
typedef __attribute__((ext_vector_type(8))) unsigned short ushort8;
typedef __attribute__((ext_vector_type(4))) unsigned short ushort4v;
typedef unsigned long long u64;

__device__ __forceinline__ unsigned short f2bf(float f) {
  unsigned u = __float_as_uint(f);
  unsigned r = (u + 0x7FFFu + ((u >> 16) & 1u)) >> 16;  // RNE (inputs finite)
  return (unsigned short)r;
}

__device__ __forceinline__ unsigned cvtpk(float a, float b) {
  unsigned r;
  asm("v_cvt_pk_bf16_f32 %0, %1, %2" : "=v"(r) : "v"(a), "v"(b));
  return r;
}

// async global->LDS, 16B per lane. LDS dest: wave-uniform base + lane*16.
__device__ __forceinline__ void gload_lds16(const void* g, void* l) {
  auto gp = (const __attribute__((address_space(1))) unsigned int*)(unsigned long long)g;
  auto lp = (__attribute__((address_space(3))) unsigned int*)(unsigned int)(unsigned long long)l;
  __builtin_amdgcn_global_load_lds(gp, lp, 16, 0, 0);
}

// ---------------- fp32 -> bf16 convert (4 weight matrices only) ----------------
__global__ __launch_bounds__(256) void cvt_w(
    const float* __restrict__ wq, const float* __restrict__ wk, const float* __restrict__ wv,
    const float* __restrict__ wo, unsigned short* __restrict__ ws)
{
  const long NW = (long)DD * DD;        // 1048576
  long i = ((long)blockIdx.x * blockDim.x + threadIdx.x) * 8;
  if (i >= 4 * NW) return;
  int s = (int)(i / NW);
  const float* src = (s == 0) ? wq : (s == 1) ? wk : (s == 2) ? wv : wo;
  long off = i - (long)s * NW;
  unsigned short* dst = ws + (long)s * NW + off;
  f32x4v a = *(const f32x4v*)(src + off);
  f32x4v b = *(const f32x4v*)(src + off + 4);
  ushort8 o;
  o[0] = f2bf(a[0]); o[1] = f2bf(a[1]); o[2] = f2bf(a[2]); o[3] = f2bf(a[3]);
  o[4] = f2bf(b[0]); o[5] = f2bf(b[1]); o[6] = f2bf(b[2]); o[7] = f2bf(b[3]);
  *(ushort8*)dst = o;
}

// ---------------- mask -> u64 bits, layout [b][tile64][q] ----------------
__global__ __launch_bounds__(256) void cvt_mask_bits(const void* __restrict__ mask,
                                                     u64* __restrict__ mb, long total64)
{
  const unsigned char* m8 = (const unsigned char*)mask;
  const int l = threadIdx.x & 63;
  unsigned probe = m8[l * 4 + 1] | m8[l * 4 + 2] | m8[l * 4 + 3];
  const bool isBool = (__any(probe != 0) != 0);   // wave-uniform, deterministic

  long t = (long)blockIdx.x * blockDim.x + threadIdx.x;
  if (t >= total64) return;
  u64 bits = 0;
  if (isBool) {
    const uint4* p = (const uint4*)(m8 + t * 64);
#pragma unroll
    for (int i = 0; i < 4; ++i) {
      uint4 q4 = p[i];
      unsigned vv[4] = {q4.x, q4.y, q4.z, q4.w};
#pragma unroll
      for (int j = 0; j < 4; ++j)
#pragma unroll
        for (int bb = 0; bb < 4; ++bb)
          bits |= (u64)((vv[j] >> (8 * bb)) & 1u) << (i * 16 + j * 4 + bb);
    }
  } else {
    const int4* p = (const int4*)((const int*)mask + t * 64);
#pragma unroll
    for (int i = 0; i < 16; ++i) {
      int4 q4 = p[i];
      bits |= (u64)(q4.x & 1) << (i * 4);
      bits |= (u64)(q4.y & 1) << (i * 4 + 1);
      bits |= (u64)(q4.z & 1) << (i * 4 + 2);
      bits |= (u64)(q4.w & 1) << (i * 4 + 3);
    }
  }
  const long bb2 = t >> 16;
  const long qq = (t >> 5) & 2047;
  const long tcol = t & 31;
  mb[(bb2 * 32 + tcol) * 2048 + qq] = bits;
}

// ---------------- GEMM: C[m,n] = (sum_k A[m,k]*W[n,k] + bias[n]) * oscale -------
// T1 XCD swizzle; T4 counted-vmcnt 3-buffer pipeline. AFP32=1 (TM must be 128):
// A fp32 -> regs (2 banks, depth-2 prefetch) -> cvt_pk -> swizzled ds_write_b128.
// Write granule fsw(r)=((r&1)<<1)|(r>>1) spreads all 4 granules (8-deep floor).
struct GemmArgs {
  const void* A;
  const unsigned short* Bw;
  const float* bias;
  void* C;
  int mode;       // 0: bf16 [m,n]; 1: fp32 [m,n]; 2: bf16 transposed per-batch
  float oscale;
};

template<int TM, int BN, int AFP32>
__global__ __launch_bounds__(256) void gemm_bt(GemmArgs ga0, GemmArgs ga1, GemmArgs ga2)
{
  constexpr int K = DD;
  constexpr int Nn = DD;
  constexpr int GX = 1024 / BN;
  constexpr int GY = 4096 / TM;
  constexpr int PERZ = GX * GY;
  constexpr int MF = TM / 32;
  constexpr int NF = BN / 32;
  constexpr int NT = K / 32;
  __shared__ __align__(16) unsigned short As[3][TM * 32];
  __shared__ __align__(16) unsigned short Bs[3][BN * 32];

  int wgid = blockIdx.x + (blockIdx.y + blockIdx.z * GY) * GX;
  const int nwg = (int)gridDim.z * PERZ;
  const int chunk = nwg >> 3;
  wgid = (wgid & 7) * chunk + (wgid >> 3);
  const int zi = wgid / PERZ;
  const int rem = wgid % PERZ;
  const int m0 = (rem / GX) * TM;
  const int n0 = (rem % GX) * BN;
  GemmArgs ga = (zi == 0) ? ga0 : ((zi == 1) ? ga1 : ga2);

  const int tid = threadIdx.x;
  const int lane = tid & 63;
  const int w = tid >> 6;
  const int m_woff = (w >> 1) * (TM / 2);
  const int n_woff = (w & 1) * (BN / 2);
  const int c = lane & 15, g = lane >> 4;

  f32x4 acc[MF][NF];
  const f32x4 z4 = {0.f, 0.f, 0.f, 0.f};
#pragma unroll
  for (int m = 0; m < MF; ++m)
#pragma unroll
    for (int n = 0; n < NF; ++n) acc[m][n] = z4;

  const unsigned short* Bb = ga.Bw + (long)n0 * K;
  const int ar = tid >> 2;
  const int ac = ((tid & 3) ^ (ar & 3)) * 8;       // B inverse-swizzled source granule

  auto STAGE_B = [&](int buf, int kk) {
#pragma unroll
    for (int i = 0; i < BN / 64; ++i)
      gload_lds16(Bb + (long)(i * 64 + ar) * K + kk + ac, &Bs[buf][i * 2048 + tid * 8]);
  };

  const unsigned short* Ab16 = (const unsigned short*)ga.A + (long)m0 * K;   // AFP32=0
  const int arow = tid >> 1;            // AFP32=1 (TM==128): 0..127
  const int ahalf = tid & 1;
  const float* Afp = (const float*)ga.A + (long)(m0 + arow) * K + ahalf * 16;
  f32x4v aregA[4], aregB[4];            // two banks: tile j in A if j even, B if odd

  auto STAGE_A16 = [&](int buf, int kk) {
#pragma unroll
    for (int i = 0; i < TM / 64; ++i)
      gload_lds16(Ab16 + (long)(i * 64 + ar) * K + kk + ac, &As[buf][i * 2048 + tid * 8]);
  };
  auto LOAD_A = [&](int kk, f32x4v (&arr)[4]) {
#pragma unroll
    for (int j = 0; j < 4; ++j) arr[j] = *(const f32x4v*)(Afp + kk + 4 * j);
  };
  auto WRITE_A = [&](int buf, f32x4v (&arr)[4]) {
    union { short8 s; unsigned u[4]; } p0, p1;
    p0.u[0] = cvtpk(arr[0][0], arr[0][1]); p0.u[1] = cvtpk(arr[0][2], arr[0][3]);
    p0.u[2] = cvtpk(arr[1][0], arr[1][1]); p0.u[3] = cvtpk(arr[1][2], arr[1][3]);
    p1.u[0] = cvtpk(arr[2][0], arr[2][1]); p1.u[1] = cvtpk(arr[2][2], arr[2][3]);
    p1.u[2] = cvtpk(arr[3][0], arr[3][1]); p1.u[3] = cvtpk(arr[3][2], arr[3][3]);
    const int fa = ((arow & 1) << 1) | ((arow >> 1) & 1);   // fsw(arow&3)
    const int G0 = (2 * ahalf) ^ fa;
    const int G1 = (2 * ahalf + 1) ^ fa;
    *(short8*)((char*)&As[buf][0] + arow * 64 + G0 * 16) = p0.s;
    *(short8*)((char*)&As[buf][0] + arow * 64 + G1 * 16) = p1.s;
  };

  if constexpr (AFP32) {
    LOAD_A(0, aregA);      // tile0
    LOAD_A(32, aregB);     // tile1
    STAGE_B(0, 0);
    STAGE_B(1, 32);
    WRITE_A(0, aregA);     // compiler waits for aregA loads
    LOAD_A(64, aregA);     // tile2
  } else {
    STAGE_A16(0, 0);
    STAGE_B(0, 0);
    STAGE_A16(1, 32);
    STAGE_B(1, 32);
  }

  const int rswz = (g ^ (c & 3)) * 8;                                   // B read
  const int aswz = AFP32 ? (g ^ (((c & 1) << 1) | ((c >> 1) & 1))) * 8  // A read (fsw)
                         : rswz;

  auto ITER = [&](int t, f32x4v (&bank)[4]) {
    if constexpr (AFP32) {
      // steady: outstanding A(t+1)4,B(t)2,A(t+2)4,B(t+1)2 -> retire 6 oldest
      if (t < NT - 2)       asm volatile("s_waitcnt vmcnt(6) lgkmcnt(0)" ::: "memory");
      else if (t == NT - 2) asm volatile("s_waitcnt vmcnt(2) lgkmcnt(0)" ::: "memory");
      else                  asm volatile("s_waitcnt vmcnt(0) lgkmcnt(0)" ::: "memory");
    } else {
      constexpr int LPS = TM / 64 + BN / 64;
      if (t < NT - 1) {
        if constexpr (LPS == 4) asm volatile("s_waitcnt vmcnt(4)" ::: "memory");
        else                    asm volatile("s_waitcnt vmcnt(3)" ::: "memory");
      } else {
        asm volatile("s_waitcnt vmcnt(0)" ::: "memory");
      }
    }
    __builtin_amdgcn_s_barrier();
    __builtin_amdgcn_sched_barrier(0);

    if constexpr (AFP32) {
      if (t + 1 < NT) WRITE_A((t + 1) % 3, bank);
      if (t + 3 < NT) LOAD_A((t + 3) * 32, bank);
      if (t + 2 < NT) STAGE_B((t + 2) % 3, (t + 2) * 32);
    } else {
      if (t + 2 < NT) { STAGE_A16((t + 2) % 3, (t + 2) * 32); STAGE_B((t + 2) % 3, (t + 2) * 32); }
    }

    const int cb = t % 3;
    short8 a[MF], b[NF];
#pragma unroll
    for (int m = 0; m < MF; ++m)
      a[m] = *(const short8*)&As[cb][(m_woff + 16 * m + c) * 32 + aswz];
#pragma unroll
    for (int n = 0; n < NF; ++n)
      b[n] = *(const short8*)&Bs[cb][(n_woff + 16 * n + c) * 32 + rswz];
    __builtin_amdgcn_s_setprio(1);
#pragma unroll
    for (int m = 0; m < MF; ++m)
#pragma unroll
      for (int n = 0; n < NF; ++n)
        acc[m][n] = __builtin_amdgcn_mfma_f32_16x16x32_bf16(a[m], b[n], acc[m][n], 0, 0, 0);
    __builtin_amdgcn_s_setprio(0);
  };

  for (int t = 0; t < NT; t += 2) {
    ITER(t, aregB);       // t even: tile t+1 odd -> bank B
    ITER(t + 1, aregA);   // t+1 odd: tile t+2 even -> bank A
  }

  // C/D layout (m89): col = lane&15, row = (lane>>4)*4 + reg
#pragma unroll
  for (int n = 0; n < NF; ++n) {
    const int col = n0 + n_woff + 16 * n + c;
    const float bv = ga.bias[col];
#pragma unroll
    for (int m = 0; m < MF; ++m) {
      const int row0 = m0 + m_woff + 16 * m + 4 * g;
      if (ga.mode == 2) {
        // V transposed [b, h*64+d, n]: 4 consecutive rows -> one 8B store
        ushort4v pk;
#pragma unroll
        for (int r = 0; r < 4; ++r) pk[r] = f2bf((acc[m][n][r] + bv) * ga.oscale);
        *(ushort4v*)&((unsigned short*)ga.C)[((long)(row0 >> 11) * DD + col) * NN + (row0 & (NN - 1))] = pk;
      } else {
#pragma unroll
        for (int r = 0; r < 4; ++r) {
          const int row = row0 + r;
          const float val = (acc[m][n][r] + bv) * ga.oscale;
          if (ga.mode == 1)
            ((float*)ga.C)[(long)row * Nn + col] = val;
          else
            ((unsigned short*)ga.C)[(long)row * Nn + col] = f2bf(val);
        }
      }
    }
  }
}

// ---------------- flash attention: split-KV 8-wave, in-register softmax ---------
// grid 512 x 512thr (2 blocks/CU, 16 waves/CU). bid&31 = (b,h), q0 = (bid>>5)*128.
// grp = w>>2: waves 0-3 do kv tiles 0..15, waves 4-7 do 16..31 (fixed-shift
// softmax is additive -> partials add). wq = w&3: q rows [q0+32wq, +32).
// 32x32x16 MFMA swapped (A=K, B=Q); T12 cvt_pk+permlane32_swap for PV A-frags.
// LDS 64KB: Ks/Vs[grp][dbuf]; epilogue combine overlays the dead K region.
__global__ __launch_bounds__(512, 4) void attn_kernel(
    const unsigned short* __restrict__ Q,
    const unsigned short* __restrict__ K,
    const unsigned short* __restrict__ Vt,
    const u64* __restrict__ mb64,
    unsigned short* __restrict__ ctx)
{
  __shared__ __align__(16) char lds_raw[65536];
  unsigned short* KsB = (unsigned short*)lds_raw;            // [grp*2+buf][4096]
  unsigned short* VsB = (unsigned short*)(lds_raw + 32768);
  float* OB = (float*)lds_raw;                               // epilogue overlay

  const int tid = threadIdx.x;
  const int lane = tid & 63;
  const int w = tid >> 6;          // 0..7
  const int grp = w >> 2;
  const int wq = w & 3;
  const int bid = blockIdx.x;
  const int b = (bid >> 4) & 1, h = bid & 15;
  const int q0 = (bid >> 5) * 128;
  const int l31 = lane & 31;
  const int hi = lane >> 5;
  const int qrow = q0 + 32 * wq + l31;

  // Q B-frags (col = q = lane&31, k = 16i + 8*hi + e)
  short8 aq[4];
  {
    const unsigned short* qp = Q + ((long)(b * NN + qrow)) * DD + h * DK + 8 * hi;
    aq[0] = *(const short8*)(qp);
    aq[1] = *(const short8*)(qp + 16);
    aq[2] = *(const short8*)(qp + 32);
    aq[3] = *(const short8*)(qp + 48);
  }

  f32x16 o0, o1, cinit;
#pragma unroll
  for (int r = 0; r < 16; ++r) { o0[r] = 0.f; o1[r] = 0.f; cinit[r] = -28.853901f; }
  float ls0 = 0.f, ls1 = 0.f;

  const unsigned short* Kbase = K + (long)(b * NN) * DD + h * DK;
  const unsigned short* Vbase = Vt + ((long)(b * DD + h * DK)) * NN;
  const u64* mbase = mb64 + (long)(b * 32) * 2048 + qrow;

  // staging: 512 threads cover one 64x64 tile per (tensor, grp)
  const int srow = tid >> 3;           // 0..63
  const int scol = tid & 7;
  const int swcol = scol ^ (srow & 7);

  auto STAGE = [&](int buf, int t) {   // stages grp0 tile t and grp1 tile t+16
    gload_lds16(Kbase + (long)(t * 64 + srow) * DD + swcol * 8, &KsB[buf * 4096 + tid * 8]);
    gload_lds16(Vbase + (long)srow * NN + t * 64 + swcol * 8, &VsB[buf * 4096 + tid * 8]);
    gload_lds16(Kbase + (long)((t + 16) * 64 + srow) * DD + swcol * 8, &KsB[(2 + buf) * 4096 + tid * 8]);
    gload_lds16(Vbase + (long)srow * NN + (t + 16) * 64 + swcol * 8, &VsB[(2 + buf) * 4096 + tid * 8]);
  };

  // hoisted loop-invariant LDS offsets (elements)
  int koffs[8], voff0[4], voff1[4];
#pragma unroll
  for (int sub = 0; sub < 2; ++sub) {
    const int krow = l31 + 32 * sub;
    const int kswz = (l31 & 7) << 3;
#pragma unroll
    for (int i = 0; i < 4; ++i)
      koffs[sub * 4 + i] = krow * 64 + ((16 * i + 8 * hi) ^ kswz);
#pragma unroll
    for (int dblk = 0; dblk < 2; ++dblk) {
      const int vrow = l31 + 32 * dblk;
      voff0[sub * 2 + dblk] = vrow * 64 + ((32 * sub + 8 * hi) ^ kswz);
      voff1[sub * 2 + dblk] = vrow * 64 + ((32 * sub + 16 + 8 * hi) ^ kswz);
    }
  }

  STAGE(0, 0);
  __syncthreads();
  int cur = 0;
  const int sh4 = 4 * hi;
  u64 mword = mbase[(long)(grp * 16) * 2048];

  for (int t = 0; t < 16; ++t) {
    const int tt = grp * 16 + t;
    const u64 mnext = (t < 15) ? mbase[(long)(tt + 1) * 2048] : 0;  // issue first
    if (t < 15) STAGE(cur ^ 1, t + 1);                              // then prefetch
    const unsigned msk0 = ((unsigned)mword) >> sh4;
    const unsigned msk1 = ((unsigned)(mword >> 32)) >> sh4;
    const unsigned short* Kt = &KsB[(grp * 2 + cur) * 4096];
    const unsigned short* Vtl = &VsB[(grp * 2 + cur) * 4096];

#pragma unroll
    for (int sub = 0; sub < 2; ++sub) {
      const unsigned m = sub ? msk1 : msk0;

      // S^T = K Q^T - 28.854  (rows = kv, cols = q)
      f32x16 ss = cinit;
      __builtin_amdgcn_s_setprio(1);
#pragma unroll
      for (int i = 0; i < 4; ++i) {
        const short8 kf = *(const short8*)&Kt[koffs[sub * 4 + i]];
        ss = __builtin_amdgcn_mfma_f32_32x32x16_bf16(kf, aq[i], ss, 0, 0, 0);
      }
      __builtin_amdgcn_s_setprio(0);

      // in-register softmax: p = exp2(S'), masked -> 0
      float p[16];
      float lacc = 0.f;
#pragma unroll
      for (int r = 0; r < 16; ++r) {
        const int cr = (r & 3) + 8 * (r >> 2);
        const float e = ((m >> cr) & 1u) ? -1e9f : ss[r];
        p[r] = __builtin_amdgcn_exp2f(e);
        lacc += p[r];
      }
      if (sub == 0) ls0 += lacc; else ls1 += lacc;

      // pack to bf16, redistribute halves for PV A-frags (T12)
      unsigned wv[8];
#pragma unroll
      for (int i = 0; i < 8; ++i) wv[i] = cvtpk(p[2 * i], p[2 * i + 1]);
      asm("v_permlane32_swap_b32 %0, %1" : "+v"(wv[0]), "+v"(wv[2]));
      asm("v_permlane32_swap_b32 %0, %1" : "+v"(wv[1]), "+v"(wv[3]));
      asm("v_permlane32_swap_b32 %0, %1" : "+v"(wv[4]), "+v"(wv[6]));
      asm("v_permlane32_swap_b32 %0, %1" : "+v"(wv[5]), "+v"(wv[7]));
      union { short8 s; unsigned u[4]; } pa0, pa1;
      pa0.u[0] = wv[0]; pa0.u[1] = wv[1]; pa0.u[2] = wv[2]; pa0.u[3] = wv[3];
      pa1.u[0] = wv[4]; pa1.u[1] = wv[5]; pa1.u[2] = wv[6]; pa1.u[3] = wv[7];

      // O += P V
      __builtin_amdgcn_s_setprio(1);
      {
        const short8 vb00 = *(const short8*)&Vtl[voff0[sub * 2 + 0]];
        const short8 vb10 = *(const short8*)&Vtl[voff1[sub * 2 + 0]];
        o0 = __builtin_amdgcn_mfma_f32_32x32x16_bf16(pa0.s, vb00, o0, 0, 0, 0);
        o0 = __builtin_amdgcn_mfma_f32_32x32x16_bf16(pa1.s, vb10, o0, 0, 0, 0);
        const short8 vb01 = *(const short8*)&Vtl[voff0[sub * 2 + 1]];
        const short8 vb11 = *(const short8*)&Vtl[voff1[sub * 2 + 1]];
        o1 = __builtin_amdgcn_mfma_f32_32x32x16_bf16(pa0.s, vb01, o1, 0, 0, 0);
        o1 = __builtin_amdgcn_mfma_f32_32x32x16_bf16(pa1.s, vb11, o1, 0, 0, 0);
      }
      __builtin_amdgcn_s_setprio(0);
    }
    __syncthreads();
    cur ^= 1;
    mword = mnext;
  }

  // ---- cross-group combine (overlay dead K/V LDS) ----
  float lsum = ls0 + ls1;
  const int li = wq * 64 + lane;       // 0..255
  if (grp == 1) {
    float* dst = OB + (long)li * 33;
#pragma unroll
    for (int r = 0; r < 16; ++r) { dst[r] = o0[r]; dst[16 + r] = o1[r]; }
    dst[32] = lsum;
  }
  __syncthreads();
  if (grp == 0) {
    const float* src = OB + (long)li * 33;
#pragma unroll
    for (int r = 0; r < 16; ++r) { o0[r] += src[r]; o1[r] += src[16 + r]; }
    lsum += src[32];
    lsum += __shfl_xor(lsum, 32);
    const float inv = 1.0f / lsum;

    // O C/D layout: col = lane&31 = d, row(reg) = (r&3)+8*(r>>2)+4*hi = q
#pragma unroll
    for (int r = 0; r < 16; ++r) {
      const int qr = (r & 3) + 8 * (r >> 2) + 4 * hi;
      const float linv = __shfl(inv, qr);
      const long row = (long)(b * NN + q0 + 32 * wq + qr);
      ctx[row * DD + h * DK + l31] = f2bf(o0[r] * linv);
      ctx[row * DD + h * DK + 32 + l31] = f2bf(o1[r] * linv);
    }
  }
}

// ---------------- launcher ----------------
extern "C" void kernel_launch(void* const* d_in, const int* in_sizes, int n_in,
                              void* d_out, int out_size, void* d_ws, size_t ws_size,
                              hipStream_t stream) {
  const float* q  = (const float*)d_in[0];
  const float* k  = (const float*)d_in[1];
  const float* v  = (const float*)d_in[2];
  const void*  mask = d_in[3];
  const float* Wq = (const float*)d_in[4];
  const float* bq = (const float*)d_in[5];
  const float* Wk = (const float*)d_in[6];
  const float* bk = (const float*)d_in[7];
  const float* Wv = (const float*)d_in[8];
  const float* bv = (const float*)d_in[9];
  const float* Wo = (const float*)d_in[10];
  const float* bo = (const float*)d_in[11];

  unsigned short* ws = (unsigned short*)d_ws;
  const long NW = (long)DD * DD;
  const long NX = (long)BB * NN * DD;
  unsigned short* Wqb = ws;
  unsigned short* Wkb = ws + NW;
  unsigned short* Wvb = ws + 2 * NW;
  unsigned short* Wob = ws + 3 * NW;
  unsigned short* Qh  = ws + 4 * NW;
  unsigned short* Kh  = Qh + NX;
  unsigned short* Vtr = Kh + NX;
  unsigned short* Ctx = Vtr + NX;
  u64* Mbits = (u64*)(Ctx + NX);
  const long NM64 = (long)BB * NN * NN / 64;   // 131072 64-bit blocks

  cvt_w<<<2048, 256, 0, stream>>>(Wq, Wk, Wv, Wo, ws);
  cvt_mask_bits<<<(int)(NM64 / 256), 256, 0, stream>>>(mask, Mbits, NM64);

  GemmArgs gq = {q, Wqb, bq, (void*)Qh, 0, LOG2E};
  GemmArgs gk = {k, Wkb, bk, (void*)Kh, 0, 1.0f};
  GemmArgs gv = {v, Wvb, bv, (void*)Vtr, 2, 1.0f};
  dim3 gproj(DD / 128, (BB * NN) / 128, 3);       // 768 blocks
  gemm_bt<128, 128, 1><<<gproj, 256, 0, stream>>>(gq, gk, gv);

  attn_kernel<<<512, 512, 0, stream>>>(Qh, Kh, Vtr, Mbits, Ctx);

  GemmArgs go = {Ctx, Wob, bo, d_out, 1, 1.0f};
  dim3 gout(DD / 128, (BB * NN) / 64, 1);         // 512 blocks
  gemm_bt<64, 128, 0><<<gout, 256, 0, stream>>>(go, go, go);
}

// Round 14
// 136.627 us; speedup vs baseline: 2.1171x; 2.1171x over previous
//
#include <hip/hip_runtime.h>
#include <math.h>

#define BB 2
#define NN 2048
#define DD 1024
#define HH 16
#define DK 64
#define LOG2E 1.4426950408889634f

typedef __attribute__((ext_vector_type(8))) short short8;
typedef __attribute__((ext_vector_type(4))) float f32x4;
typedef __attribute__((ext_vector_type(16))) float f32x16;
typedef __attribute__((ext_vector_type(4))) float f32x4v;
typedef __attribute__((ext_vector_type(8))) unsigned short ushort8;
typedef __attribute__((ext_vector_type(4))) unsigned short ushort4v;
typedef unsigned long long u64;

__device__ __forceinline__ unsigned short f2bf(float f) {
  unsigned u = __float_as_uint(f);
  unsigned r = (u + 0x7FFFu + ((u >> 16) & 1u)) >> 16;  // RNE (inputs finite)
  return (unsigned short)r;
}

__device__ __forceinline__ unsigned cvtpk(float a, float b) {
  unsigned r;
  asm("v_cvt_pk_bf16_f32 %0, %1, %2" : "=v"(r) : "v"(a), "v"(b));
  return r;
}

// async global->LDS, 16B per lane. LDS dest: wave-uniform base + lane*16.
__device__ __forceinline__ void gload_lds16(const void* g, void* l) {
  auto gp = (const __attribute__((address_space(1))) unsigned int*)(unsigned long long)g;
  auto lp = (__attribute__((address_space(3))) unsigned int*)(unsigned int)(unsigned long long)l;
  __builtin_amdgcn_global_load_lds(gp, lp, 16, 0, 0);
}

// ---------------- fp32 -> bf16 convert (4 weight matrices only) ----------------
__global__ __launch_bounds__(256) void cvt_w(
    const float* __restrict__ wq, const float* __restrict__ wk, const float* __restrict__ wv,
    const float* __restrict__ wo, unsigned short* __restrict__ ws)
{
  const long NW = (long)DD * DD;        // 1048576
  long i = ((long)blockIdx.x * blockDim.x + threadIdx.x) * 8;
  if (i >= 4 * NW) return;
  int s = (int)(i / NW);
  const float* src = (s == 0) ? wq : (s == 1) ? wk : (s == 2) ? wv : wo;
  long off = i - (long)s * NW;
  unsigned short* dst = ws + (long)s * NW + off;
  f32x4v a = *(const f32x4v*)(src + off);
  f32x4v b = *(const f32x4v*)(src + off + 4);
  ushort8 o;
  o[0] = f2bf(a[0]); o[1] = f2bf(a[1]); o[2] = f2bf(a[2]); o[3] = f2bf(a[3]);
  o[4] = f2bf(b[0]); o[5] = f2bf(b[1]); o[6] = f2bf(b[2]); o[7] = f2bf(b[3]);
  *(ushort8*)dst = o;
}

// ---------------- mask -> u64 bits, layout [b][tile64][q] ----------------
__global__ __launch_bounds__(256) void cvt_mask_bits(const void* __restrict__ mask,
                                                     u64* __restrict__ mb, long total64)
{
  const unsigned char* m8 = (const unsigned char*)mask;
  const int l = threadIdx.x & 63;
  unsigned probe = m8[l * 4 + 1] | m8[l * 4 + 2] | m8[l * 4 + 3];
  const bool isBool = (__any(probe != 0) != 0);   // wave-uniform, deterministic

  long t = (long)blockIdx.x * blockDim.x + threadIdx.x;
  if (t >= total64) return;
  u64 bits = 0;
  if (isBool) {
    const uint4* p = (const uint4*)(m8 + t * 64);
#pragma unroll
    for (int i = 0; i < 4; ++i) {
      uint4 q4 = p[i];
      unsigned vv[4] = {q4.x, q4.y, q4.z, q4.w};
#pragma unroll
      for (int j = 0; j < 4; ++j)
#pragma unroll
        for (int bb = 0; bb < 4; ++bb)
          bits |= (u64)((vv[j] >> (8 * bb)) & 1u) << (i * 16 + j * 4 + bb);
    }
  } else {
    const int4* p = (const int4*)((const int*)mask + t * 64);
#pragma unroll
    for (int i = 0; i < 16; ++i) {
      int4 q4 = p[i];
      bits |= (u64)(q4.x & 1) << (i * 4);
      bits |= (u64)(q4.y & 1) << (i * 4 + 1);
      bits |= (u64)(q4.z & 1) << (i * 4 + 2);
      bits |= (u64)(q4.w & 1) << (i * 4 + 3);
    }
  }
  const long bb2 = t >> 16;
  const long qq = (t >> 5) & 2047;
  const long tcol = t & 31;
  mb[(bb2 * 32 + tcol) * 2048 + qq] = bits;
}

// ---------------- GEMM: C[m,n] = (sum_k A[m,k]*W[n,k] + bias[n]) * oscale -------
// T1 XCD swizzle; T4 counted-vmcnt 3-buffer pipeline. AFP32=1 (TM must be 128):
// A fp32 -> regs (2 banks, depth-2 prefetch) -> cvt_pk -> swizzled ds_write_b128.
// Write granule fsw(r)=((r&1)<<1)|(r>>1) spreads all 4 granules (8-deep floor).
struct GemmArgs {
  const void* A;
  const unsigned short* Bw;
  const float* bias;
  void* C;
  int mode;       // 0: bf16 [m,n]; 1: fp32 [m,n]; 2: bf16 transposed per-batch
  float oscale;
};

template<int TM, int BN, int AFP32>
__global__ __launch_bounds__(256) void gemm_bt(GemmArgs ga0, GemmArgs ga1, GemmArgs ga2)
{
  constexpr int K = DD;
  constexpr int Nn = DD;
  constexpr int GX = 1024 / BN;
  constexpr int GY = 4096 / TM;
  constexpr int PERZ = GX * GY;
  constexpr int MF = TM / 32;
  constexpr int NF = BN / 32;
  constexpr int NT = K / 32;
  __shared__ __align__(16) unsigned short As[3][TM * 32];
  __shared__ __align__(16) unsigned short Bs[3][BN * 32];

  int wgid = blockIdx.x + (blockIdx.y + blockIdx.z * GY) * GX;
  const int nwg = (int)gridDim.z * PERZ;
  const int chunk = nwg >> 3;
  wgid = (wgid & 7) * chunk + (wgid >> 3);
  const int zi = wgid / PERZ;
  const int rem = wgid % PERZ;
  const int m0 = (rem / GX) * TM;
  const int n0 = (rem % GX) * BN;
  GemmArgs ga = (zi == 0) ? ga0 : ((zi == 1) ? ga1 : ga2);

  const int tid = threadIdx.x;
  const int lane = tid & 63;
  const int w = tid >> 6;
  const int m_woff = (w >> 1) * (TM / 2);
  const int n_woff = (w & 1) * (BN / 2);
  const int c = lane & 15, g = lane >> 4;

  f32x4 acc[MF][NF];
  const f32x4 z4 = {0.f, 0.f, 0.f, 0.f};
#pragma unroll
  for (int m = 0; m < MF; ++m)
#pragma unroll
    for (int n = 0; n < NF; ++n) acc[m][n] = z4;

  const unsigned short* Bb = ga.Bw + (long)n0 * K;
  const int ar = tid >> 2;
  const int ac = ((tid & 3) ^ (ar & 3)) * 8;       // B inverse-swizzled source granule

  auto STAGE_B = [&](int buf, int kk) {
#pragma unroll
    for (int i = 0; i < BN / 64; ++i)
      gload_lds16(Bb + (long)(i * 64 + ar) * K + kk + ac, &Bs[buf][i * 2048 + tid * 8]);
  };

  const unsigned short* Ab16 = (const unsigned short*)ga.A + (long)m0 * K;   // AFP32=0
  const int arow = tid >> 1;            // AFP32=1 (TM==128): 0..127
  const int ahalf = tid & 1;
  const float* Afp = (const float*)ga.A + (long)(m0 + arow) * K + ahalf * 16;
  f32x4v aregA[4], aregB[4];            // two banks: tile j in A if j even, B if odd

  auto STAGE_A16 = [&](int buf, int kk) {
#pragma unroll
    for (int i = 0; i < TM / 64; ++i)
      gload_lds16(Ab16 + (long)(i * 64 + ar) * K + kk + ac, &As[buf][i * 2048 + tid * 8]);
  };
  auto LOAD_A = [&](int kk, f32x4v (&arr)[4]) {
#pragma unroll
    for (int j = 0; j < 4; ++j) arr[j] = *(const f32x4v*)(Afp + kk + 4 * j);
  };
  auto WRITE_A = [&](int buf, f32x4v (&arr)[4]) {
    union { short8 s; unsigned u[4]; } p0, p1;
    p0.u[0] = cvtpk(arr[0][0], arr[0][1]); p0.u[1] = cvtpk(arr[0][2], arr[0][3]);
    p0.u[2] = cvtpk(arr[1][0], arr[1][1]); p0.u[3] = cvtpk(arr[1][2], arr[1][3]);
    p1.u[0] = cvtpk(arr[2][0], arr[2][1]); p1.u[1] = cvtpk(arr[2][2], arr[2][3]);
    p1.u[2] = cvtpk(arr[3][0], arr[3][1]); p1.u[3] = cvtpk(arr[3][2], arr[3][3]);
    const int fa = ((arow & 1) << 1) | ((arow >> 1) & 1);   // fsw(arow&3)
    const int G0 = (2 * ahalf) ^ fa;
    const int G1 = (2 * ahalf + 1) ^ fa;
    *(short8*)((char*)&As[buf][0] + arow * 64 + G0 * 16) = p0.s;
    *(short8*)((char*)&As[buf][0] + arow * 64 + G1 * 16) = p1.s;
  };

  if constexpr (AFP32) {
    LOAD_A(0, aregA);      // tile0
    LOAD_A(32, aregB);     // tile1
    STAGE_B(0, 0);
    STAGE_B(1, 32);
    WRITE_A(0, aregA);     // compiler waits for aregA loads
    LOAD_A(64, aregA);     // tile2
  } else {
    STAGE_A16(0, 0);
    STAGE_B(0, 0);
    STAGE_A16(1, 32);
    STAGE_B(1, 32);
  }

  const int rswz = (g ^ (c & 3)) * 8;                                   // B read
  const int aswz = AFP32 ? (g ^ (((c & 1) << 1) | ((c >> 1) & 1))) * 8  // A read (fsw)
                         : rswz;

  auto ITER = [&](int t, f32x4v (&bank)[4]) {
    if constexpr (AFP32) {
      if (t < NT - 2)       asm volatile("s_waitcnt vmcnt(6) lgkmcnt(0)" ::: "memory");
      else if (t == NT - 2) asm volatile("s_waitcnt vmcnt(2) lgkmcnt(0)" ::: "memory");
      else                  asm volatile("s_waitcnt vmcnt(0) lgkmcnt(0)" ::: "memory");
    } else {
      constexpr int LPS = TM / 64 + BN / 64;
      if (t < NT - 1) {
        if constexpr (LPS == 4) asm volatile("s_waitcnt vmcnt(4)" ::: "memory");
        else                    asm volatile("s_waitcnt vmcnt(3)" ::: "memory");
      } else {
        asm volatile("s_waitcnt vmcnt(0)" ::: "memory");
      }
    }
    __builtin_amdgcn_s_barrier();
    __builtin_amdgcn_sched_barrier(0);

    if constexpr (AFP32) {
      if (t + 1 < NT) WRITE_A((t + 1) % 3, bank);
      if (t + 3 < NT) LOAD_A((t + 3) * 32, bank);
      if (t + 2 < NT) STAGE_B((t + 2) % 3, (t + 2) * 32);
    } else {
      if (t + 2 < NT) { STAGE_A16((t + 2) % 3, (t + 2) * 32); STAGE_B((t + 2) % 3, (t + 2) * 32); }
    }

    const int cb = t % 3;
    short8 a[MF], b[NF];
#pragma unroll
    for (int m = 0; m < MF; ++m)
      a[m] = *(const short8*)&As[cb][(m_woff + 16 * m + c) * 32 + aswz];
#pragma unroll
    for (int n = 0; n < NF; ++n)
      b[n] = *(const short8*)&Bs[cb][(n_woff + 16 * n + c) * 32 + rswz];
    __builtin_amdgcn_s_setprio(1);
#pragma unroll
    for (int m = 0; m < MF; ++m)
#pragma unroll
      for (int n = 0; n < NF; ++n)
        acc[m][n] = __builtin_amdgcn_mfma_f32_16x16x32_bf16(a[m], b[n], acc[m][n], 0, 0, 0);
    __builtin_amdgcn_s_setprio(0);
  };

  for (int t = 0; t < NT; t += 2) {
    ITER(t, aregB);       // t even: tile t+1 odd -> bank B
    ITER(t + 1, aregA);   // t+1 odd: tile t+2 even -> bank A
  }

  // C/D layout (m89): col = lane&15, row = (lane>>4)*4 + reg
#pragma unroll
  for (int n = 0; n < NF; ++n) {
    const int col = n0 + n_woff + 16 * n + c;
    const float bv = ga.bias[col];
#pragma unroll
    for (int m = 0; m < MF; ++m) {
      const int row0 = m0 + m_woff + 16 * m + 4 * g;
      if (ga.mode == 2) {
        ushort4v pk;
#pragma unroll
        for (int r = 0; r < 4; ++r) pk[r] = f2bf((acc[m][n][r] + bv) * ga.oscale);
        *(ushort4v*)&((unsigned short*)ga.C)[((long)(row0 >> 11) * DD + col) * NN + (row0 & (NN - 1))] = pk;
      } else {
#pragma unroll
        for (int r = 0; r < 4; ++r) {
          const int row = row0 + r;
          const float val = (acc[m][n][r] + bv) * ga.oscale;
          if (ga.mode == 1)
            ((float*)ga.C)[(long)row * Nn + col] = val;
          else
            ((unsigned short*)ga.C)[(long)row * Nn + col] = f2bf(val);
        }
      }
    }
  }
}

// ---------------- flash attention: split-KV 8-wave, in-register softmax ---------
// grid 512 x 512thr. NO launch_bounds occupancy clamp (round-13 lesson: (512,4)
// capped VGPRs at ~64 -> 430 MB scratch spill). LDS 64 KB -> 2 blocks/CU if
// VGPR <= 128; softmax/pack fused per-pair to keep live range small.
__global__ __launch_bounds__(512) void attn_kernel(
    const unsigned short* __restrict__ Q,
    const unsigned short* __restrict__ K,
    const unsigned short* __restrict__ Vt,
    const u64* __restrict__ mb64,
    unsigned short* __restrict__ ctx)
{
  __shared__ __align__(16) char lds_raw[65536];
  unsigned short* KsB = (unsigned short*)lds_raw;            // [grp*2+buf][4096]
  unsigned short* VsB = (unsigned short*)(lds_raw + 32768);
  float* OB = (float*)lds_raw;                               // epilogue overlay

  const int tid = threadIdx.x;
  const int lane = tid & 63;
  const int w = tid >> 6;          // 0..7
  const int grp = w >> 2;
  const int wq = w & 3;
  const int bid = blockIdx.x;
  const int b = (bid >> 4) & 1, h = bid & 15;
  const int q0 = (bid >> 5) * 128;
  const int l31 = lane & 31;
  const int hi = lane >> 5;
  const int qrow = q0 + 32 * wq + l31;

  // Q B-frags (col = q = lane&31, k = 16i + 8*hi + e)
  short8 aq[4];
  {
    const unsigned short* qp = Q + ((long)(b * NN + qrow)) * DD + h * DK + 8 * hi;
    aq[0] = *(const short8*)(qp);
    aq[1] = *(const short8*)(qp + 16);
    aq[2] = *(const short8*)(qp + 32);
    aq[3] = *(const short8*)(qp + 48);
  }

  f32x16 o0, o1, cinit;
#pragma unroll
  for (int r = 0; r < 16; ++r) { o0[r] = 0.f; o1[r] = 0.f; cinit[r] = -28.853901f; }
  float ls0 = 0.f, ls1 = 0.f;

  const unsigned short* Kbase = K + (long)(b * NN) * DD + h * DK;
  const unsigned short* Vbase = Vt + ((long)(b * DD + h * DK)) * NN;
  const u64* mbase = mb64 + (long)(b * 32) * 2048 + qrow;

  const int srow = tid >> 3;           // 0..63
  const int scol = tid & 7;
  const int swcol = scol ^ (srow & 7);

  auto STAGE = [&](int buf, int t) {   // stages grp0 tile t and grp1 tile t+16
    gload_lds16(Kbase + (long)(t * 64 + srow) * DD + swcol * 8, &KsB[buf * 4096 + tid * 8]);
    gload_lds16(Vbase + (long)srow * NN + t * 64 + swcol * 8, &VsB[buf * 4096 + tid * 8]);
    gload_lds16(Kbase + (long)((t + 16) * 64 + srow) * DD + swcol * 8, &KsB[(2 + buf) * 4096 + tid * 8]);
    gload_lds16(Vbase + (long)srow * NN + (t + 16) * 64 + swcol * 8, &VsB[(2 + buf) * 4096 + tid * 8]);
  };

  // hoisted loop-invariant LDS offsets (elements)
  int koffs[8], voff0[4], voff1[4];
#pragma unroll
  for (int sub = 0; sub < 2; ++sub) {
    const int krow = l31 + 32 * sub;
    const int kswz = (l31 & 7) << 3;
#pragma unroll
    for (int i = 0; i < 4; ++i)
      koffs[sub * 4 + i] = krow * 64 + ((16 * i + 8 * hi) ^ kswz);
#pragma unroll
    for (int dblk = 0; dblk < 2; ++dblk) {
      const int vrow = l31 + 32 * dblk;
      voff0[sub * 2 + dblk] = vrow * 64 + ((32 * sub + 8 * hi) ^ kswz);
      voff1[sub * 2 + dblk] = vrow * 64 + ((32 * sub + 16 + 8 * hi) ^ kswz);
    }
  }

  STAGE(0, 0);
  __syncthreads();
  int cur = 0;
  const int sh4 = 4 * hi;
  u64 mword = mbase[(long)(grp * 16) * 2048];

  for (int t = 0; t < 16; ++t) {
    const int tt = grp * 16 + t;
    const u64 mnext = (t < 15) ? mbase[(long)(tt + 1) * 2048] : 0;  // issue first
    if (t < 15) STAGE(cur ^ 1, t + 1);                              // then prefetch
    const unsigned msk0 = ((unsigned)mword) >> sh4;
    const unsigned msk1 = ((unsigned)(mword >> 32)) >> sh4;
    const unsigned short* Kt = &KsB[(grp * 2 + cur) * 4096];
    const unsigned short* Vtl = &VsB[(grp * 2 + cur) * 4096];

#pragma unroll
    for (int sub = 0; sub < 2; ++sub) {
      const unsigned m = sub ? msk1 : msk0;

      // S^T = K Q^T - 28.854  (rows = kv, cols = q)
      f32x16 ss = cinit;
      __builtin_amdgcn_s_setprio(1);
#pragma unroll
      for (int i = 0; i < 4; ++i) {
        const short8 kf = *(const short8*)&Kt[koffs[sub * 4 + i]];
        ss = __builtin_amdgcn_mfma_f32_32x32x16_bf16(kf, aq[i], ss, 0, 0, 0);
      }
      __builtin_amdgcn_s_setprio(0);

      // fused softmax+pack: p = exp2(S') (masked->0), immediately packed (short
      // live range, round-13 spill lesson); per-lane partial denominator.
      unsigned wv[8];
      float lacc = 0.f;
#pragma unroll
      for (int i = 0; i < 8; ++i) {
        const int r0 = 2 * i, r1 = 2 * i + 1;
        const int cr0 = (r0 & 3) + 8 * (r0 >> 2);
        const int cr1 = (r1 & 3) + 8 * (r1 >> 2);
        const float e0 = ((m >> cr0) & 1u) ? -1e9f : ss[r0];
        const float e1 = ((m >> cr1) & 1u) ? -1e9f : ss[r1];
        const float p0 = __builtin_amdgcn_exp2f(e0);
        const float p1 = __builtin_amdgcn_exp2f(e1);
        lacc += p0 + p1;
        wv[i] = cvtpk(p0, p1);
      }
      if (sub == 0) ls0 += lacc; else ls1 += lacc;

      asm("v_permlane32_swap_b32 %0, %1" : "+v"(wv[0]), "+v"(wv[2]));
      asm("v_permlane32_swap_b32 %0, %1" : "+v"(wv[1]), "+v"(wv[3]));
      asm("v_permlane32_swap_b32 %0, %1" : "+v"(wv[4]), "+v"(wv[6]));
      asm("v_permlane32_swap_b32 %0, %1" : "+v"(wv[5]), "+v"(wv[7]));
      union { short8 s; unsigned u[4]; } pa0, pa1;
      pa0.u[0] = wv[0]; pa0.u[1] = wv[1]; pa0.u[2] = wv[2]; pa0.u[3] = wv[3];
      pa1.u[0] = wv[4]; pa1.u[1] = wv[5]; pa1.u[2] = wv[6]; pa1.u[3] = wv[7];

      // O += P V
      __builtin_amdgcn_s_setprio(1);
      {
        const short8 vb00 = *(const short8*)&Vtl[voff0[sub * 2 + 0]];
        const short8 vb10 = *(const short8*)&Vtl[voff1[sub * 2 + 0]];
        o0 = __builtin_amdgcn_mfma_f32_32x32x16_bf16(pa0.s, vb00, o0, 0, 0, 0);
        o0 = __builtin_amdgcn_mfma_f32_32x32x16_bf16(pa1.s, vb10, o0, 0, 0, 0);
        const short8 vb01 = *(const short8*)&Vtl[voff0[sub * 2 + 1]];
        const short8 vb11 = *(const short8*)&Vtl[voff1[sub * 2 + 1]];
        o1 = __builtin_amdgcn_mfma_f32_32x32x16_bf16(pa0.s, vb01, o1, 0, 0, 0);
        o1 = __builtin_amdgcn_mfma_f32_32x32x16_bf16(pa1.s, vb11, o1, 0, 0, 0);
      }
      __builtin_amdgcn_s_setprio(0);
    }
    __syncthreads();
    cur ^= 1;
    mword = mnext;
  }

  // ---- cross-group combine (overlay dead K/V LDS) ----
  float lsum = ls0 + ls1;
  const int li = wq * 64 + lane;       // 0..255
  if (grp == 1) {
    float* dst = OB + (long)li * 33;
#pragma unroll
    for (int r = 0; r < 16; ++r) { dst[r] = o0[r]; dst[16 + r] = o1[r]; }
    dst[32] = lsum;
  }
  __syncthreads();
  if (grp == 0) {
    const float* src = OB + (long)li * 33;
#pragma unroll
    for (int r = 0; r < 16; ++r) { o0[r] += src[r]; o1[r] += src[16 + r]; }
    lsum += src[32];
    lsum += __shfl_xor(lsum, 32);
    const float inv = 1.0f / lsum;

    // O C/D layout: col = lane&31 = d, row(reg) = (r&3)+8*(r>>2)+4*hi = q
#pragma unroll
    for (int r = 0; r < 16; ++r) {
      const int qr = (r & 3) + 8 * (r >> 2) + 4 * hi;
      const float linv = __shfl(inv, qr);
      const long row = (long)(b * NN + q0 + 32 * wq + qr);
      ctx[row * DD + h * DK + l31] = f2bf(o0[r] * linv);
      ctx[row * DD + h * DK + 32 + l31] = f2bf(o1[r] * linv);
    }
  }
}

// ---------------- launcher ----------------
extern "C" void kernel_launch(void* const* d_in, const int* in_sizes, int n_in,
                              void* d_out, int out_size, void* d_ws, size_t ws_size,
                              hipStream_t stream) {
  const float* q  = (const float*)d_in[0];
  const float* k  = (const float*)d_in[1];
  const float* v  = (const float*)d_in[2];
  const void*  mask = d_in[3];
  const float* Wq = (const float*)d_in[4];
  const float* bq = (const float*)d_in[5];
  const float* Wk = (const float*)d_in[6];
  const float* bk = (const float*)d_in[7];
  const float* Wv = (const float*)d_in[8];
  const float* bv = (const float*)d_in[9];
  const float* Wo = (const float*)d_in[10];
  const float* bo = (const float*)d_in[11];

  unsigned short* ws = (unsigned short*)d_ws;
  const long NW = (long)DD * DD;
  const long NX = (long)BB * NN * DD;
  unsigned short* Wqb = ws;
  unsigned short* Wkb = ws + NW;
  unsigned short* Wvb = ws + 2 * NW;
  unsigned short* Wob = ws + 3 * NW;
  unsigned short* Qh  = ws + 4 * NW;
  unsigned short* Kh  = Qh + NX;
  unsigned short* Vtr = Kh + NX;
  unsigned short* Ctx = Vtr + NX;
  u64* Mbits = (u64*)(Ctx + NX);
  const long NM64 = (long)BB * NN * NN / 64;   // 131072 64-bit blocks

  cvt_w<<<2048, 256, 0, stream>>>(Wq, Wk, Wv, Wo, ws);
  cvt_mask_bits<<<(int)(NM64 / 256), 256, 0, stream>>>(mask, Mbits, NM64);

  GemmArgs gq = {q, Wqb, bq, (void*)Qh, 0, LOG2E};
  GemmArgs gk = {k, Wkb, bk, (void*)Kh, 0, 1.0f};
  GemmArgs gv = {v, Wvb, bv, (void*)Vtr, 2, 1.0f};
  dim3 gproj(DD / 128, (BB * NN) / 128, 3);       // 768 blocks
  gemm_bt<128, 128, 1><<<gproj, 256, 0, stream>>>(gq, gk, gv);

  attn_kernel<<<512, 512, 0, stream>>>(Qh, Kh, Vtr, Mbits, Ctx);

  GemmArgs go = {Ctx, Wob, bo, d_out, 1, 1.0f};
  dim3 gout(DD / 128, (BB * NN) / 64, 1);         // 512 blocks
  gemm_bt<64, 128, 0><<<gout, 256, 0, stream>>>(go, go, go);
}

// Round 15
// 130.071 us; speedup vs baseline: 2.2238x; 1.0504x over previous
//
#include <hip/hip_runtime.h>
#include <math.h>

#define BB 2
#define NN 2048
#define DD 1024
#define HH 16
#define DK 64
#define LOG2E 1.4426950408889634f

typedef __attribute__((ext_vector_type(8))) short short8;
typedef __attribute__((ext_vector_type(4))) float f32x4;
typedef __attribute__((ext_vector_type(16))) float f32x16;
typedef __attribute__((ext_vector_type(4))) float f32x4v;
typedef __attribute__((ext_vector_type(8))) unsigned short ushort8;
typedef __attribute__((ext_vector_type(4))) unsigned short ushort4v;
typedef unsigned long long u64;

__device__ __forceinline__ unsigned short f2bf(float f) {
  unsigned u = __float_as_uint(f);
  unsigned r = (u + 0x7FFFu + ((u >> 16) & 1u)) >> 16;  // RNE (inputs finite)
  return (unsigned short)r;
}

__device__ __forceinline__ unsigned cvtpk(float a, float b) {
  unsigned r;
  asm("v_cvt_pk_bf16_f32 %0, %1, %2" : "=v"(r) : "v"(a), "v"(b));
  return r;
}

// async global->LDS, 16B per lane. LDS dest: wave-uniform base + lane*16.
__device__ __forceinline__ void gload_lds16(const void* g, void* l) {
  auto gp = (const __attribute__((address_space(1))) unsigned int*)(unsigned long long)g;
  auto lp = (__attribute__((address_space(3))) unsigned int*)(unsigned int)(unsigned long long)l;
  __builtin_amdgcn_global_load_lds(gp, lp, 16, 0, 0);
}

// ---------------- fp32 -> bf16 convert (q,k,v + 4 weights) ----------------
// Reverted from the AFP32-fused GEMM (r12-r14): reg-staged A conversion inside
// the GEMM measured 77-96 us vs 61 us for gload_lds staging; a separate
// BW-bound cvt pass (~17 us) is net faster.
__global__ __launch_bounds__(256) void cvt_all(
    const float* __restrict__ q, const float* __restrict__ k, const float* __restrict__ v,
    const float* __restrict__ wq, const float* __restrict__ wk, const float* __restrict__ wv,
    const float* __restrict__ wo, unsigned short* __restrict__ ws)
{
  const long NW = (long)DD * DD;        // 1048576
  const long NX = (long)BB * NN * DD;   // 4194304
  long i = ((long)blockIdx.x * blockDim.x + threadIdx.x) * 8;
  if (i >= 4 * NW + 3 * NX) return;
  const float* src; unsigned short* dst; long off;
  if (i < 4 * NW) {
    int s = (int)(i / NW);
    src = (s == 0) ? wq : (s == 1) ? wk : (s == 2) ? wv : wo;
    off = i - (long)s * NW;
    dst = ws + (long)s * NW + off;
  } else {
    long j = i - 4 * NW;
    int s = (int)(j / NX);
    src = (s == 0) ? q : (s == 1) ? k : v;
    off = j - (long)s * NX;
    dst = ws + 4 * NW + (long)s * NX + off;
  }
  f32x4v a = *(const f32x4v*)(src + off);
  f32x4v b = *(const f32x4v*)(src + off + 4);
  ushort8 o;
  o[0] = f2bf(a[0]); o[1] = f2bf(a[1]); o[2] = f2bf(a[2]); o[3] = f2bf(a[3]);
  o[4] = f2bf(b[0]); o[5] = f2bf(b[1]); o[6] = f2bf(b[2]); o[7] = f2bf(b[3]);
  *(ushort8*)dst = o;
}

// ---------------- mask -> u64 bits, layout [b][tile64][q] ----------------
__global__ __launch_bounds__(256) void cvt_mask_bits(const void* __restrict__ mask,
                                                     u64* __restrict__ mb, long total64)
{
  const unsigned char* m8 = (const unsigned char*)mask;
  const int l = threadIdx.x & 63;
  unsigned probe = m8[l * 4 + 1] | m8[l * 4 + 2] | m8[l * 4 + 3];
  const bool isBool = (__any(probe != 0) != 0);   // wave-uniform, deterministic

  long t = (long)blockIdx.x * blockDim.x + threadIdx.x;
  if (t >= total64) return;
  u64 bits = 0;
  if (isBool) {
    const uint4* p = (const uint4*)(m8 + t * 64);
#pragma unroll
    for (int i = 0; i < 4; ++i) {
      uint4 q4 = p[i];
      unsigned vv[4] = {q4.x, q4.y, q4.z, q4.w};
#pragma unroll
      for (int j = 0; j < 4; ++j)
#pragma unroll
        for (int bb = 0; bb < 4; ++bb)
          bits |= (u64)((vv[j] >> (8 * bb)) & 1u) << (i * 16 + j * 4 + bb);
    }
  } else {
    const int4* p = (const int4*)((const int*)mask + t * 64);
#pragma unroll
    for (int i = 0; i < 16; ++i) {
      int4 q4 = p[i];
      bits |= (u64)(q4.x & 1) << (i * 4);
      bits |= (u64)(q4.y & 1) << (i * 4 + 1);
      bits |= (u64)(q4.z & 1) << (i * 4 + 2);
      bits |= (u64)(q4.w & 1) << (i * 4 + 3);
    }
  }
  const long bb2 = t >> 16;
  const long qq = (t >> 5) & 2047;
  const long tcol = t & 31;
  mb[(bb2 * 32 + tcol) * 2048 + qq] = bits;
}

// ---------------- GEMM: C[m,n] = (sum_k A[m,k]*W[n,k] + bias[n]) * oscale -------
// Round-11 proven config: TM x BN tile, BK=32, 4 waves (2x2), gload_lds staging
// for A and B, T1 XCD-chunked swizzle, T4 counted-vmcnt 3-buffer pipeline
// (stages t+1, t+2 in flight across the barrier; never vmcnt(0) mid-loop).
struct GemmArgs {
  const unsigned short* A;
  const unsigned short* Bw;
  const float* bias;
  void* C;
  int mode;       // 0: bf16 [m,n]; 1: fp32 [m,n]; 2: bf16 transposed per-batch
  float oscale;
};

template<int TM, int BN>
__global__ __launch_bounds__(256) void gemm_bt(GemmArgs ga0, GemmArgs ga1, GemmArgs ga2)
{
  constexpr int K = DD;
  constexpr int Nn = DD;
  constexpr int GX = 1024 / BN;
  constexpr int GY = 4096 / TM;
  constexpr int PERZ = GX * GY;
  constexpr int MF = TM / 32;
  constexpr int NF = BN / 32;
  constexpr int NT = K / 32;
  constexpr int LPS = TM / 64 + BN / 64;   // gload_lds per thread per stage
  __shared__ __align__(16) unsigned short As[3][TM * 32];
  __shared__ __align__(16) unsigned short Bs[3][BN * 32];

  // XCD-chunked bijective swizzle (nwg % 8 == 0)
  int wgid = blockIdx.x + (blockIdx.y + blockIdx.z * GY) * GX;
  const int nwg = (int)gridDim.z * PERZ;
  const int chunk = nwg >> 3;
  wgid = (wgid & 7) * chunk + (wgid >> 3);
  const int zi = wgid / PERZ;
  const int rem = wgid % PERZ;
  const int m0 = (rem / GX) * TM;
  const int n0 = (rem % GX) * BN;
  GemmArgs ga = (zi == 0) ? ga0 : ((zi == 1) ? ga1 : ga2);

  const int tid = threadIdx.x;
  const int lane = tid & 63;
  const int w = tid >> 6;
  const int m_woff = (w >> 1) * (TM / 2);
  const int n_woff = (w & 1) * (BN / 2);
  const int c = lane & 15, g = lane >> 4;

  f32x4 acc[MF][NF];
  const f32x4 z4 = {0.f, 0.f, 0.f, 0.f};
#pragma unroll
  for (int m = 0; m < MF; ++m)
#pragma unroll
    for (int n = 0; n < NF; ++n) acc[m][n] = z4;

  const unsigned short* Ab = ga.A + (long)m0 * K;
  const unsigned short* Bb = ga.Bw + (long)n0 * K;
  const int ar = tid >> 2;
  const int ac = ((tid & 3) ^ (ar & 3)) * 8;       // inverse-swizzled source granule

  auto STAGE = [&](int buf, int kk) {
#pragma unroll
    for (int i = 0; i < TM / 64; ++i)
      gload_lds16(Ab + (long)(i * 64 + ar) * K + kk + ac, &As[buf][i * 2048 + tid * 8]);
#pragma unroll
    for (int i = 0; i < BN / 64; ++i)
      gload_lds16(Bb + (long)(i * 64 + ar) * K + kk + ac, &Bs[buf][i * 2048 + tid * 8]);
  };

  STAGE(0, 0);
  STAGE(1, 32);

  const int rswz = (g ^ (c & 3)) * 8;   // swizzled k-granule for ds_read

  for (int t = 0; t < NT; ++t) {
    // counted wait: stage t retired; stages t+1, t+2 remain in flight (T4)
    if (t < NT - 1) {
      if constexpr (LPS == 4)
        asm volatile("s_waitcnt vmcnt(4)" ::: "memory");
      else
        asm volatile("s_waitcnt vmcnt(3)" ::: "memory");
    } else {
      asm volatile("s_waitcnt vmcnt(0)" ::: "memory");
    }
    __builtin_amdgcn_s_barrier();
    __builtin_amdgcn_sched_barrier(0);
    if (t + 2 < NT) STAGE((t + 2) % 3, (t + 2) * 32);

    const int cb = t % 3;
    short8 a[MF], b[NF];
#pragma unroll
    for (int m = 0; m < MF; ++m)
      a[m] = *(const short8*)&As[cb][(m_woff + 16 * m + c) * 32 + rswz];
#pragma unroll
    for (int n = 0; n < NF; ++n)
      b[n] = *(const short8*)&Bs[cb][(n_woff + 16 * n + c) * 32 + rswz];
    __builtin_amdgcn_s_setprio(1);
#pragma unroll
    for (int m = 0; m < MF; ++m)
#pragma unroll
      for (int n = 0; n < NF; ++n)
        acc[m][n] = __builtin_amdgcn_mfma_f32_16x16x32_bf16(a[m], b[n], acc[m][n], 0, 0, 0);
    __builtin_amdgcn_s_setprio(0);
  }

  // C/D layout (m89): col = lane&15, row = (lane>>4)*4 + reg
#pragma unroll
  for (int n = 0; n < NF; ++n) {
    const int col = n0 + n_woff + 16 * n + c;
    const float bv = ga.bias[col];
#pragma unroll
    for (int m = 0; m < MF; ++m) {
      const int row0 = m0 + m_woff + 16 * m + 4 * g;
      if (ga.mode == 2) {
        // V transposed [b, h*64+d, n]: 4 consecutive rows -> one 8B store
        ushort4v pk;
#pragma unroll
        for (int r = 0; r < 4; ++r) pk[r] = f2bf((acc[m][n][r] + bv) * ga.oscale);
        *(ushort4v*)&((unsigned short*)ga.C)[((long)(row0 >> 11) * DD + col) * NN + (row0 & (NN - 1))] = pk;
      } else {
#pragma unroll
        for (int r = 0; r < 4; ++r) {
          const int row = row0 + r;
          const float val = (acc[m][n][r] + bv) * ga.oscale;
          if (ga.mode == 1)
            ((float*)ga.C)[(long)row * Nn + col] = val;
          else
            ((unsigned short*)ga.C)[(long)row * Nn + col] = f2bf(val);
        }
      }
    }
  }
}

// ---------------- flash attention: split-KV 8-wave, in-register softmax ---------
// (round-14 verbatim — attn dropped out of the top-5 with this version)
__global__ __launch_bounds__(512) void attn_kernel(
    const unsigned short* __restrict__ Q,
    const unsigned short* __restrict__ K,
    const unsigned short* __restrict__ Vt,
    const u64* __restrict__ mb64,
    unsigned short* __restrict__ ctx)
{
  __shared__ __align__(16) char lds_raw[65536];
  unsigned short* KsB = (unsigned short*)lds_raw;            // [grp*2+buf][4096]
  unsigned short* VsB = (unsigned short*)(lds_raw + 32768);
  float* OB = (float*)lds_raw;                               // epilogue overlay

  const int tid = threadIdx.x;
  const int lane = tid & 63;
  const int w = tid >> 6;          // 0..7
  const int grp = w >> 2;
  const int wq = w & 3;
  const int bid = blockIdx.x;
  const int b = (bid >> 4) & 1, h = bid & 15;
  const int q0 = (bid >> 5) * 128;
  const int l31 = lane & 31;
  const int hi = lane >> 5;
  const int qrow = q0 + 32 * wq + l31;

  // Q B-frags (col = q = lane&31, k = 16i + 8*hi + e)
  short8 aq[4];
  {
    const unsigned short* qp = Q + ((long)(b * NN + qrow)) * DD + h * DK + 8 * hi;
    aq[0] = *(const short8*)(qp);
    aq[1] = *(const short8*)(qp + 16);
    aq[2] = *(const short8*)(qp + 32);
    aq[3] = *(const short8*)(qp + 48);
  }

  f32x16 o0, o1, cinit;
#pragma unroll
  for (int r = 0; r < 16; ++r) { o0[r] = 0.f; o1[r] = 0.f; cinit[r] = -28.853901f; }
  float ls0 = 0.f, ls1 = 0.f;

  const unsigned short* Kbase = K + (long)(b * NN) * DD + h * DK;
  const unsigned short* Vbase = Vt + ((long)(b * DD + h * DK)) * NN;
  const u64* mbase = mb64 + (long)(b * 32) * 2048 + qrow;

  const int srow = tid >> 3;           // 0..63
  const int scol = tid & 7;
  const int swcol = scol ^ (srow & 7);

  auto STAGE = [&](int buf, int t) {   // stages grp0 tile t and grp1 tile t+16
    gload_lds16(Kbase + (long)(t * 64 + srow) * DD + swcol * 8, &KsB[buf * 4096 + tid * 8]);
    gload_lds16(Vbase + (long)srow * NN + t * 64 + swcol * 8, &VsB[buf * 4096 + tid * 8]);
    gload_lds16(Kbase + (long)((t + 16) * 64 + srow) * DD + swcol * 8, &KsB[(2 + buf) * 4096 + tid * 8]);
    gload_lds16(Vbase + (long)srow * NN + (t + 16) * 64 + swcol * 8, &VsB[(2 + buf) * 4096 + tid * 8]);
  };

  // hoisted loop-invariant LDS offsets (elements)
  int koffs[8], voff0[4], voff1[4];
#pragma unroll
  for (int sub = 0; sub < 2; ++sub) {
    const int krow = l31 + 32 * sub;
    const int kswz = (l31 & 7) << 3;
#pragma unroll
    for (int i = 0; i < 4; ++i)
      koffs[sub * 4 + i] = krow * 64 + ((16 * i + 8 * hi) ^ kswz);
#pragma unroll
    for (int dblk = 0; dblk < 2; ++dblk) {
      const int vrow = l31 + 32 * dblk;
      voff0[sub * 2 + dblk] = vrow * 64 + ((32 * sub + 8 * hi) ^ kswz);
      voff1[sub * 2 + dblk] = vrow * 64 + ((32 * sub + 16 + 8 * hi) ^ kswz);
    }
  }

  STAGE(0, 0);
  __syncthreads();
  int cur = 0;
  const int sh4 = 4 * hi;
  u64 mword = mbase[(long)(grp * 16) * 2048];

  for (int t = 0; t < 16; ++t) {
    const int tt = grp * 16 + t;
    const u64 mnext = (t < 15) ? mbase[(long)(tt + 1) * 2048] : 0;  // issue first
    if (t < 15) STAGE(cur ^ 1, t + 1);                              // then prefetch
    const unsigned msk0 = ((unsigned)mword) >> sh4;
    const unsigned msk1 = ((unsigned)(mword >> 32)) >> sh4;
    const unsigned short* Kt = &KsB[(grp * 2 + cur) * 4096];
    const unsigned short* Vtl = &VsB[(grp * 2 + cur) * 4096];

#pragma unroll
    for (int sub = 0; sub < 2; ++sub) {
      const unsigned m = sub ? msk1 : msk0;

      // S^T = K Q^T - 28.854  (rows = kv, cols = q)
      f32x16 ss = cinit;
      __builtin_amdgcn_s_setprio(1);
#pragma unroll
      for (int i = 0; i < 4; ++i) {
        const short8 kf = *(const short8*)&Kt[koffs[sub * 4 + i]];
        ss = __builtin_amdgcn_mfma_f32_32x32x16_bf16(kf, aq[i], ss, 0, 0, 0);
      }
      __builtin_amdgcn_s_setprio(0);

      // fused softmax+pack: p = exp2(S') (masked->0), short live range
      unsigned wv[8];
      float lacc = 0.f;
#pragma unroll
      for (int i = 0; i < 8; ++i) {
        const int r0 = 2 * i, r1 = 2 * i + 1;
        const int cr0 = (r0 & 3) + 8 * (r0 >> 2);
        const int cr1 = (r1 & 3) + 8 * (r1 >> 2);
        const float e0 = ((m >> cr0) & 1u) ? -1e9f : ss[r0];
        const float e1 = ((m >> cr1) & 1u) ? -1e9f : ss[r1];
        const float p0 = __builtin_amdgcn_exp2f(e0);
        const float p1 = __builtin_amdgcn_exp2f(e1);
        lacc += p0 + p1;
        wv[i] = cvtpk(p0, p1);
      }
      if (sub == 0) ls0 += lacc; else ls1 += lacc;

      asm("v_permlane32_swap_b32 %0, %1" : "+v"(wv[0]), "+v"(wv[2]));
      asm("v_permlane32_swap_b32 %0, %1" : "+v"(wv[1]), "+v"(wv[3]));
      asm("v_permlane32_swap_b32 %0, %1" : "+v"(wv[4]), "+v"(wv[6]));
      asm("v_permlane32_swap_b32 %0, %1" : "+v"(wv[5]), "+v"(wv[7]));
      union { short8 s; unsigned u[4]; } pa0, pa1;
      pa0.u[0] = wv[0]; pa0.u[1] = wv[1]; pa0.u[2] = wv[2]; pa0.u[3] = wv[3];
      pa1.u[0] = wv[4]; pa1.u[1] = wv[5]; pa1.u[2] = wv[6]; pa1.u[3] = wv[7];

      // O += P V
      __builtin_amdgcn_s_setprio(1);
      {
        const short8 vb00 = *(const short8*)&Vtl[voff0[sub * 2 + 0]];
        const short8 vb10 = *(const short8*)&Vtl[voff1[sub * 2 + 0]];
        o0 = __builtin_amdgcn_mfma_f32_32x32x16_bf16(pa0.s, vb00, o0, 0, 0, 0);
        o0 = __builtin_amdgcn_mfma_f32_32x32x16_bf16(pa1.s, vb10, o0, 0, 0, 0);
        const short8 vb01 = *(const short8*)&Vtl[voff0[sub * 2 + 1]];
        const short8 vb11 = *(const short8*)&Vtl[voff1[sub * 2 + 1]];
        o1 = __builtin_amdgcn_mfma_f32_32x32x16_bf16(pa0.s, vb01, o1, 0, 0, 0);
        o1 = __builtin_amdgcn_mfma_f32_32x32x16_bf16(pa1.s, vb11, o1, 0, 0, 0);
      }
      __builtin_amdgcn_s_setprio(0);
    }
    __syncthreads();
    cur ^= 1;
    mword = mnext;
  }

  // ---- cross-group combine (overlay dead K/V LDS) ----
  float lsum = ls0 + ls1;
  const int li = wq * 64 + lane;       // 0..255
  if (grp == 1) {
    float* dst = OB + (long)li * 33;
#pragma unroll
    for (int r = 0; r < 16; ++r) { dst[r] = o0[r]; dst[16 + r] = o1[r]; }
    dst[32] = lsum;
  }
  __syncthreads();
  if (grp == 0) {
    const float* src = OB + (long)li * 33;
#pragma unroll
    for (int r = 0; r < 16; ++r) { o0[r] += src[r]; o1[r] += src[16 + r]; }
    lsum += src[32];
    lsum += __shfl_xor(lsum, 32);
    const float inv = 1.0f / lsum;

    // O C/D layout: col = lane&31 = d, row(reg) = (r&3)+8*(r>>2)+4*hi = q
#pragma unroll
    for (int r = 0; r < 16; ++r) {
      const int qr = (r & 3) + 8 * (r >> 2) + 4 * hi;
      const float linv = __shfl(inv, qr);
      const long row = (long)(b * NN + q0 + 32 * wq + qr);
      ctx[row * DD + h * DK + l31] = f2bf(o0[r] * linv);
      ctx[row * DD + h * DK + 32 + l31] = f2bf(o1[r] * linv);
    }
  }
}

// ---------------- launcher ----------------
extern "C" void kernel_launch(void* const* d_in, const int* in_sizes, int n_in,
                              void* d_out, int out_size, void* d_ws, size_t ws_size,
                              hipStream_t stream) {
  const float* q  = (const float*)d_in[0];
  const float* k  = (const float*)d_in[1];
  const float* v  = (const float*)d_in[2];
  const void*  mask = d_in[3];
  const float* Wq = (const float*)d_in[4];
  const float* bq = (const float*)d_in[5];
  const float* Wk = (const float*)d_in[6];
  const float* bk = (const float*)d_in[7];
  const float* Wv = (const float*)d_in[8];
  const float* bv = (const float*)d_in[9];
  const float* Wo = (const float*)d_in[10];
  const float* bo = (const float*)d_in[11];

  unsigned short* ws = (unsigned short*)d_ws;
  const long NW = (long)DD * DD;
  const long NX = (long)BB * NN * DD;
  unsigned short* Wqb = ws;
  unsigned short* Wkb = ws + NW;
  unsigned short* Wvb = ws + 2 * NW;
  unsigned short* Wob = ws + 3 * NW;
  unsigned short* Xq  = ws + 4 * NW;
  unsigned short* Xk  = Xq + NX;
  unsigned short* Xv  = Xk + NX;
  unsigned short* Qh  = Xv + NX;
  unsigned short* Kh  = Qh + NX;
  unsigned short* Vtr = Kh + NX;
  unsigned short* Ctx = Vtr + NX;
  u64* Mbits = (u64*)(Ctx + NX);
  const long NM64 = (long)BB * NN * NN / 64;   // 131072 64-bit blocks

  cvt_all<<<8192, 256, 0, stream>>>(q, k, v, Wq, Wk, Wv, Wo, ws);
  cvt_mask_bits<<<(int)(NM64 / 256), 256, 0, stream>>>(mask, Mbits, NM64);

  GemmArgs gq = {Xq, Wqb, bq, (void*)Qh, 0, LOG2E};
  GemmArgs gk = {Xk, Wkb, bk, (void*)Kh, 0, 1.0f};
  GemmArgs gv = {Xv, Wvb, bv, (void*)Vtr, 2, 1.0f};
  dim3 gproj(DD / 128, (BB * NN) / 128, 3);       // 768 blocks
  gemm_bt<128, 128><<<gproj, 256, 0, stream>>>(gq, gk, gv);

  attn_kernel<<<512, 512, 0, stream>>>(Qh, Kh, Vtr, Mbits, Ctx);

  GemmArgs go = {Ctx, Wob, bo, d_out, 1, 1.0f};
  dim3 gout(DD / 128, (BB * NN) / 64, 1);         // 512 blocks
  gemm_bt<64, 128><<<gout, 256, 0, stream>>>(go, go, go);
}